// Round 4
// baseline (82.114 us; speedup 1.0000x reference)
//
#include <hip/hip_runtime.h>

#define GRID_N 16384
#define NLAYERS 8
#define NPOS 32
#define BATCH 32
#define MW 4096          // output width
#define TILE 32
#define HALO 16          // 2 * NLAYERS
#define WBUF 64          // TILE + 2*HALO
#define ROWP 36          // padded row stride: 144B, 16B-aligned, full-BW rotation pattern

// v4: barrier-minimal. 512 blocks x 512 threads (2 blocks/CU).
// Wave ty owns batches 4ty..4ty+3 for ALL 64 column slots (lane = column) ->
// state is wave-private-sliced: single-buffered st[64][36], ZERO barriers for
// state (per-wave in-order DS + wave_barrier against compiler reordering).
// Gates staged 4 layers at a time (twl[4][64][36]); only 3 real barriers total
// (+1 before the transposed output). Gate logits for the 2nd group prefetched
// into 16 regs with ~4 layers of compute to cover latency.
__global__ __launch_bounds__(512, 4) void ASIC_44186623541335_kernel(
    const float* __restrict__ x,    // (32, 4096)
    const float* __restrict__ tg,   // (8, 32, 16384) raw logits
    float* __restrict__ out)        // (32, 4096)
{
    __shared__ __align__(16) float st[WBUF][ROWP];        // 9.2 KB, single buffer
    __shared__ __align__(16) float twl[4][WBUF][ROWP];    // 36.9 KB, 4 layers of gates

    const int tid = threadIdx.x;
    const int tx  = tid & 63;        // column slot (lane)
    const int ty  = tid >> 6;        // 0..7 -> batches 4ty..4ty+3, gate cols 4ty..4ty+3
    const int c0  = 4 * ty;
    const int start = blockIdx.x * TILE;
    const int gcol  = (start - HALO + tx) & (GRID_N - 1);

    // ---- prefetch gate logits for layers 0..3 (coalesced across lanes) ----
    float pf[16];
    #pragma unroll
    for (int l4 = 0; l4 < 4; ++l4)
        #pragma unroll
        for (int k = 0; k < 4; ++k)
            pf[l4 * 4 + k] = tg[((size_t)l4 * NPOS + c0 + k) * GRID_N + gcol];

    // ---- init state: embed x at stride 4, zeros elsewhere ----
    for (int f = tid; f < WBUF * BATCH; f += 512) {
        const int b = f >> 6;        // batch
        const int j = f & 63;        // column slot (lane-consecutive -> coalesced x)
        const int g = (start - HALO + j) & (GRID_N - 1);
        st[j][b] = ((g & 3) == 0) ? x[b * MW + (g >> 2)] : 0.0f;
    }

    // ---- stage layers 0..3 (sigmoid once), prefetch layers 4..7 ----
    #pragma unroll
    for (int l4 = 0; l4 < 4; ++l4) {
        float4 sg;
        sg.x = __builtin_amdgcn_rcpf(1.0f + __expf(-pf[l4 * 4 + 0]));
        sg.y = __builtin_amdgcn_rcpf(1.0f + __expf(-pf[l4 * 4 + 1]));
        sg.z = __builtin_amdgcn_rcpf(1.0f + __expf(-pf[l4 * 4 + 2]));
        sg.w = __builtin_amdgcn_rcpf(1.0f + __expf(-pf[l4 * 4 + 3]));
        *(float4*)&twl[l4][tx][c0] = sg;
    }
    #pragma unroll
    for (int l4 = 0; l4 < 4; ++l4)
        #pragma unroll
        for (int k = 0; k < 4; ++k)
            pf[l4 * 4 + k] = tg[((size_t)(4 + l4) * NPOS + c0 + k) * GRID_N + gcol];
    __syncthreads();   // barrier 1: gates(0..3) + embedded state visible

    for (int l = 0; l < NLAYERS; ++l) {
        const int h     = 2 * (NLAYERS - 1 - l);
        const int ncols = TILE + 2 * h;          // 60,56,...,32
        const int j     = (HALO - h) + tx;

        if (tx < ncols) {
            // gates for this column -> 32 regs (8x ds_read_b128)
            float tw[32];
            #pragma unroll
            for (int k = 0; k < 8; ++k) {
                const float4 q = *(const float4*)&twl[l & 3][j][4 * k];
                tw[4 * k]     = q.x; tw[4 * k + 1] = q.y;
                tw[4 * k + 2] = q.z; tw[4 * k + 3] = q.w;
            }

            float4 res;
            #pragma unroll
            for (int p = 0; p < 2; ++p) {
                // per-pair state loads (b64): 2 batches x 5 neighbor columns
                const float2 S0 = *(const float2*)&st[j - 2][c0 + 2 * p];
                const float2 S1 = *(const float2*)&st[j - 1][c0 + 2 * p];
                const float2 S2 = *(const float2*)&st[j    ][c0 + 2 * p];
                const float2 S3 = *(const float2*)&st[j + 1][c0 + 2 * p];
                const float2 S4 = *(const float2*)&st[j + 2][c0 + 2 * p];

                // 5-level lerp tree == multilinear interpolation of tw
                float ua[16], ub[16];
                #pragma unroll
                for (int r = 0; r < 16; ++r) {
                    const float d = tw[16 + r] - tw[r];   // batch-invariant
                    ua[r] = fmaf(S0.x, d, tw[r]);
                    ub[r] = fmaf(S0.y, d, tw[r]);
                }
                #pragma unroll
                for (int r = 0; r < 8; ++r) {
                    const float da = ua[8 + r] - ua[r], db = ub[8 + r] - ub[r];
                    ua[r] = fmaf(S1.x, da, ua[r]);
                    ub[r] = fmaf(S1.y, db, ub[r]);
                }
                #pragma unroll
                for (int r = 0; r < 4; ++r) {
                    const float da = ua[4 + r] - ua[r], db = ub[4 + r] - ub[r];
                    ua[r] = fmaf(S2.x, da, ua[r]);
                    ub[r] = fmaf(S2.y, db, ub[r]);
                }
                #pragma unroll
                for (int r = 0; r < 2; ++r) {
                    const float da = ua[2 + r] - ua[r], db = ub[2 + r] - ub[r];
                    ua[r] = fmaf(S3.x, da, ua[r]);
                    ub[r] = fmaf(S3.y, db, ub[r]);
                }
                const float da = ua[1] - ua[0], db = ub[1] - ub[0];
                float ra = fmaf(S4.x, da, ua[0]);
                float rb = fmaf(S4.y, db, ub[0]);
                ra = fminf(fmaxf(ra, 0.0f), 1.0f);
                rb = fminf(fmaxf(rb, 0.0f), 1.0f);
                if (p) { res.z = ra; res.w = rb; } else { res.x = ra; res.y = rb; }
            }
            *(float4*)&st[j][c0] = res;   // wave-private slice: no barrier needed
        }
        // forbid compiler hoisting next layer's LDS reads above this write;
        // HW executes a wave's DS ops in order, so cross-lane RAW is safe.
        __builtin_amdgcn_wave_barrier();

        if (l == 3) {
            __syncthreads();   // barrier 2: everyone done reading gates(0..3)
            #pragma unroll
            for (int l4 = 0; l4 < 4; ++l4) {
                float4 sg;
                sg.x = __builtin_amdgcn_rcpf(1.0f + __expf(-pf[l4 * 4 + 0]));
                sg.y = __builtin_amdgcn_rcpf(1.0f + __expf(-pf[l4 * 4 + 1]));
                sg.z = __builtin_amdgcn_rcpf(1.0f + __expf(-pf[l4 * 4 + 2]));
                sg.w = __builtin_amdgcn_rcpf(1.0f + __expf(-pf[l4 * 4 + 3]));
                *(float4*)&twl[l4][tx][c0] = sg;
            }
            __syncthreads();   // barrier 3: gates(4..7) visible
        }
    }

    __syncthreads();           // barrier 4: final state visible for transposed output
    // ---- output: state[:, ::4] for this tile's 32 owned columns ----
    if (tid < 256) {
        const int c4 = tid & 7;          // output column within tile
        const int b  = tid >> 3;         // batch
        out[b * MW + (start >> 2) + c4] = st[HALO + 4 * c4][b];
    }
}

extern "C" void kernel_launch(void* const* d_in, const int* in_sizes, int n_in,
                              void* d_out, int out_size, void* d_ws, size_t ws_size,
                              hipStream_t stream) {
    const float* x  = (const float*)d_in[0];   // (32, 4096)
    const float* tg = (const float*)d_in[1];   // (8, 32, 16384)
    float* out = (float*)d_out;                // (32, 4096)
    ASIC_44186623541335_kernel<<<GRID_N / TILE, 512, 0, stream>>>(x, tg, out);
}